// Round 12
// baseline (258.210 us; speedup 1.0000x reference)
//
#include <hip/hip_runtime.h>

// Correlation layer: in1,in2 [8,256,128,128] f32 -> out [8,81,128,128] f32
// out[b, dy*9+dx, y, x] = mean_c in1[b,c,y,x] * in2pad[b,c,y+dy,x+dx], pad=4
//
// v12: tile 16x32 (staged 24x40 -> in2 requests 302->252 MB), 16 waves, 1 row x
// 32 px (2 n-tiles) per wave. 8-ch steps: S2 (f32, 30KB halves, dbuf) -> F
// (bf16 frags, 60KB, single-buf; step h of chunk fills kb=h). K=32 MFMA every
// 4th step. in1: 16-float reg prefetch per chunk (named ping-pong bufs).
// Two-rendezvous/step schedule; exact keep-counts vmcnt(2)/(1), A-step (18)/(17).

#define B_   8
#define C_   256
#define H_   128
#define W_   128
#define ND   9
#define TY   16
#define TW   32
#define CS   (H_ * W_)
#define SB2F 7680                // floats per S2 half (8ch*24*40)
#define FOFFB 61440
#define LDS_TOTAL 122880

typedef short v8s __attribute__((ext_vector_type(8)));
typedef float v4f __attribute__((ext_vector_type(4)));

__device__ __forceinline__ unsigned short f2bf(float f) {
    union { float f; unsigned u; } v; v.f = f;
    return (unsigned short)((v.u + 0x7FFFu + ((v.u >> 16) & 1u)) >> 16);
}

__device__ __forceinline__ void dma16(const float* g, void* lds) {
    __builtin_amdgcn_global_load_lds(
        (const __attribute__((address_space(1))) void*)g,
        (__attribute__((address_space(3))) void*)lds, 16, 0, 0);
}

#define FENCE()      asm volatile("" ::: "memory")
// keep = ops issued this step (G only): w<14: 2, w>=14: 1
#define WAITK_BAR() do {                                                          \
        if (w < 14) asm volatile("s_waitcnt vmcnt(2)\n\ts_barrier" ::: "memory"); \
        else        asm volatile("s_waitcnt vmcnt(1)\n\ts_barrier" ::: "memory"); \
    } while (0)
// A-issue step: keep = 16 A-loads + G
#define WAITKA_BAR() do {                                                          \
        if (w < 14) asm volatile("s_waitcnt vmcnt(18)\n\ts_barrier" ::: "memory"); \
        else        asm volatile("s_waitcnt vmcnt(17)\n\ts_barrier" ::: "memory"); \
    } while (0)
#define WAITV0_BAR() asm volatile("s_waitcnt vmcnt(0)\n\ts_barrier" ::: "memory")
#define LGKM0_BAR()  asm volatile("s_waitcnt lgkmcnt(0)\n\ts_barrier" ::: "memory")
#define LGKM0()      asm volatile("s_waitcnt lgkmcnt(0)" ::: "memory")

__global__ __launch_bounds__(1024, 1)
void corr_mfma_kernel(const float* __restrict__ in1,
                      const float* __restrict__ in2,
                      float* __restrict__ out) {
    extern __shared__ __align__(16) char ldsbase[];
    float* S2 = (float*)ldsbase;               // [2][8ch][24r][40j] f32
    short* F  = (short*)(ldsbase + FOFFB);     // [4kb][960 rj][8e] bf16
    float* EP = (float*)ldsbase;               // epilogue alias (S2 free then)

    const int tid  = threadIdx.x;
    const int lane = tid & 63;
    const int w    = tid >> 6;                 // wave 0..15 = output row

    const int lin = blockIdx.x;                // 256 blocks, 1/CU
    const int b   = lin & 7;                   // batch == XCD
    const int idx = lin >> 3;                  // 0..31
    const int x0  = (idx & 3) * TW;
    const int y0  = (idx >> 2) * TY;

    const int i_px = lane & 15;
    const int kb   = lane >> 4;

    // ---- in2 DMA descriptors: 30 instr/step; waves 0-13: 2, waves 14-15: 1 ----
    const float* dsrc[2];
    int ddst[2];
    #pragma unroll
    for (int t = 0; t < 2; ++t) {
        if (t == 1 && w >= 14) { dsrc[t] = in2; ddst[t] = 0; continue; }
        const int q   = (w < 14) ? (w * 2 + t) : (28 + (w - 14));   // 0..29
        const int g   = q * 64 + lane;         // 0..1919
        const int ch  = g / 240;               // channel within 8-ch step
        const int rem = g % 240;
        const int r   = rem / 10;              // staged row 0..23
        const int jg  = rem % 10;              // 4-col granule
        int gy = y0 - 4 + r;
        int gx = x0 - 4 + jg * 4;
        gy = gy < 0 ? 0 : (gy > H_ - 1 ? H_ - 1 : gy);
        gx = gx < 0 ? 0 : (gx > W_ - 4 ? W_ - 4 : gx);   // pad=4 == granule
        dsrc[t] = in2 + ((long)(b * C_) + ch) * CS + gy * W_ + gx;
        ddst[t] = q * 1024;
    }

    // ---- in1 base: lane's pixel column, kb's channel-octet ----
    const float* pA =
        in1 + ((long)b * C_ + kb * 8) * CS + (long)(y0 + w) * W_ + x0 + i_px;

    // ---- convert descriptor: 960 items/step, 1/thread (waves 0-14) ----
    const bool cact = (w < 15);
    const int  crr  = tid / 40, cjj = tid % 40;
    const bool cval = cact && ((unsigned)(y0 - 4 + crr) < (unsigned)H_) &&
                              ((unsigned)(x0 - 4 + cjj) < (unsigned)W_);

    v4f acc0[2][ND];
    v4f acc1[2][5];
    #pragma unroll
    for (int t = 0; t < 2; ++t) {
        #pragma unroll
        for (int d = 0; d < ND; ++d) acc0[t][d] = (v4f)0.0f;
        #pragma unroll
        for (int p = 0; p < 5; ++p)  acc1[t][p] = (v4f)0.0f;
    }
    float bufA[16], bufB[16];
    v8s afA[2], afB[2];

#define ISSUE_G(s_) do {                                                      \
        const long so = (long)(s_) * 8 * CS;                                  \
        char* dst = (char*)S2 + ((s_) & 1) * 30720;                           \
        dma16(dsrc[0] + so, dst + ddst[0]);                                   \
        if (w < 14) dma16(dsrc[1] + so, dst + ddst[1]);                       \
        FENCE();                                                              \
    } while (0)

#define ISSUE_A(cn_, buf_) do {                                               \
        _Pragma("unroll")                                                     \
        for (int t = 0; t < 2; ++t)                                           \
            _Pragma("unroll")                                                 \
            for (int e = 0; e < 8; ++e)                                       \
                buf_[t * 8 + e] = pA[((long)(cn_) * 32 + e) * CS + t * 16];   \
        FENCE();                                                              \
    } while (0)

#define AFRAG(buf_, af_) do {                                                 \
        _Pragma("unroll")                                                     \
        for (int t = 0; t < 2; ++t)                                           \
            _Pragma("unroll")                                                 \
            for (int e = 0; e < 8; ++e)                                       \
                af_[t][e] = (short)f2bf(buf_[t * 8 + e]);                     \
    } while (0)

#define CONVERT(s_) do {                                                      \
        if (cact) {                                                           \
            const float* sh = S2 + ((s_) & 1) * SB2F;                         \
            v8s pk;                                                           \
            _Pragma("unroll")                                                 \
            for (int e = 0; e < 8; ++e)                                       \
                pk[e] = (short)f2bf(sh[e * 960 + tid]);                       \
            if (!cval) pk = (v8s)0;                                           \
            *(v8s*)&F[(((s_) % 4) * 960 + tid) * 8] = pk;                     \
        }                                                                     \
    } while (0)

#define MFMA_C(af_) do {                                                      \
        _Pragma("unroll")                                                     \
        for (int t = 0; t < 2; ++t) {                                         \
            _Pragma("unroll")                                                 \
            for (int dy = 0; dy < ND; ++dy) {                                 \
                const v8s f = *(const v8s*)&F[(kb * 960 + (w + dy) * 40 + t * 16 + i_px) * 8]; \
                acc0[t][dy] = __builtin_amdgcn_mfma_f32_16x16x32_bf16(        \
                    af_[t], f, acc0[t][dy], 0, 0, 0);                         \
            }                                                                 \
            const int hi = i_px >> 3, j1 = t * 16 + 16 + (i_px & 7);          \
            _Pragma("unroll")                                                 \
            for (int P = 0; P < 5; ++P) {                                     \
                int r = w + 2 * P + hi;                                       \
                if (r > 23) r = 23;        /* garbage lanes, never read */    \
                const v8s f = *(const v8s*)&F[(kb * 960 + r * 40 + j1) * 8];  \
                acc1[t][P] = __builtin_amdgcn_mfma_f32_16x16x32_bf16(         \
                    af_[t], f, acc1[t][P], 0, 0, 0);                          \
            }                                                                 \
        }                                                                     \
    } while (0)

    // chunk c: steps 4c..4c+3; afc = current A frags, afn/bufn = next chunk's
#define CHUNK(c_, afc_, afn_, bufn_) do {                                     \
        ISSUE_G(4*(c_)+2); WAITK_BAR();  CONVERT(4*(c_)+1); LGKM0_BAR();      \
        ISSUE_G(4*(c_)+3); WAITK_BAR();  CONVERT(4*(c_)+2); LGKM0_BAR();      \
        ISSUE_A((c_)+1, bufn_);                                               \
        ISSUE_G(4*(c_)+4); WAITKA_BAR(); CONVERT(4*(c_)+3); LGKM0_BAR();      \
        ISSUE_G(4*(c_)+5); MFMA_C(afc_); WAITK_BAR();                         \
        CONVERT(4*(c_)+4); AFRAG(bufn_, afn_); LGKM0_BAR();                   \
    } while (0)

    // ---- prologue ----
    ISSUE_A(0, bufA);
    ISSUE_G(0);
    ISSUE_G(1);
    WAITK_BAR();                 // retire A(0)+G(0); keep G(1)
    AFRAG(bufA, afA);
    CONVERT(0);
    LGKM0_BAR();

    // ---- 8 chunks = 32 steps ----
    CHUNK(0, afA, afB, bufB);
    CHUNK(1, afB, afA, bufA);
    CHUNK(2, afA, afB, bufB);
    CHUNK(3, afB, afA, bufA);
    CHUNK(4, afA, afB, bufB);
    CHUNK(5, afB, afA, bufA);
    CHUNK(6, afA, afB, bufB);
    // peeled steps 28..31 (chunk 7)
    ISSUE_G(30); WAITK_BAR();  CONVERT(29); LGKM0_BAR();
    ISSUE_G(31); WAITK_BAR();  CONVERT(30); LGKM0_BAR();
    WAITV0_BAR();              CONVERT(31); LGKM0_BAR();
    MFMA_C(afB);

    // ---- epilogue: 1 row x 2 n-tiles per wave, wave-private EP (aliases S2) ----
    float* epw = EP + w * 384;
    const int g4 = lane >> 4;
    #pragma unroll
    for (int t = 0; t < 2; ++t) {
        #pragma unroll
        for (int dy = 0; dy < ND; ++dy) {
            #pragma unroll
            for (int q = 0; q < 4; ++q)
                epw[(g4 * 4 + q) * 24 + i_px] = acc0[t][dy][q];
            if ((i_px >> 3) == (dy & 1)) {
                #pragma unroll
                for (int q = 0; q < 4; ++q)
                    epw[(g4 * 4 + q) * 24 + 16 + (i_px & 7)] = acc1[t][dy >> 1][q];
            }
            LGKM0();
            #pragma unroll
            for (int rep = 0; rep < 3; ++rep) {
                const int dx = g4 + rep * 4;
                if (dx < 9) {
                    const float v = epw[i_px * 24 + i_px + dx] * (1.0f / 256.0f);
                    out[(((long)b * 81 + dy * 9 + dx) * CS) + (y0 + w) * W_ + x0 + t * 16 + i_px] = v;
                }
            }
            LGKM0();
        }
    }
#undef ISSUE_G
#undef ISSUE_A
#undef AFRAG
#undef CONVERT
#undef MFMA_C
#undef CHUNK
}

extern "C" void kernel_launch(void* const* d_in, const int* in_sizes, int n_in,
                              void* d_out, int out_size, void* d_ws, size_t ws_size,
                              hipStream_t stream) {
    const float* in1 = (const float*)d_in[0];
    const float* in2 = (const float*)d_in[1];
    float* outp      = (float*)d_out;
    (void)hipFuncSetAttribute((const void*)corr_mfma_kernel,
                              hipFuncAttributeMaxDynamicSharedMemorySize,
                              LDS_TOTAL);
    corr_mfma_kernel<<<256, 1024, LDS_TOTAL, stream>>>(in1, in2, outp);
}

// Round 13
// 224.008 us; speedup vs baseline: 1.1527x; 1.1527x over previous
//
#include <hip/hip_runtime.h>

// Correlation layer: in1,in2 [8,256,128,128] f32 -> out [8,81,128,128] f32
// out[b, dy*9+dx, y, x] = mean_c in1[b,c,y,x] * in2pad[b,c,y+dy,x+dx], pad=4
//
// v13: 16x32 tile (staged 24x40 -> in2 252 MB) + v11's zero-reg-state recipe:
// BOTH inputs through global_load_lds. 8-ch steps; S2 (in2 f32) 2x30K dbuf;
// F (bf16 frags, 4 kb-groups, group s%4 filled per step) 60K single-buf;
// S1 (in1 f32) 2x16K ring; per-lane A-frag built from own-kb slab in region B
// (only reg state: 2x2 v8s ping-pong). 1024 thr / 16 waves, 1 row x 32 px,
// acc 28 v4f. K=32 MFMA at step 4c+3. Two-rendezvous; keep vmcnt(3)/(2).

#define B_   8
#define C_   256
#define H_   128
#define W_   128
#define ND   9
#define TY   16
#define TW   32
#define CS   (H_ * W_)
#define SB2F 7680                 // floats per S2 half (8ch*24*40)
#define FOFFB  61440
#define S1OFFB 122880
#define LDS_TOTAL 155648

typedef short v8s __attribute__((ext_vector_type(8)));
typedef float v4f __attribute__((ext_vector_type(4)));

__device__ __forceinline__ unsigned short f2bf(float f) {
    union { float f; unsigned u; } v; v.f = f;
    return (unsigned short)((v.u + 0x7FFFu + ((v.u >> 16) & 1u)) >> 16);
}

__device__ __forceinline__ void dma16(const float* g, void* lds) {
    __builtin_amdgcn_global_load_lds(
        (const __attribute__((address_space(1))) void*)g,
        (__attribute__((address_space(3))) void*)lds, 16, 0, 0);
}

#define FENCE()      asm volatile("" ::: "memory")
// retire G(s+1), keep G(s+2): per-wave ops/G = 3 (w<14) or 2 (w>=14)
#define WAITK_BAR() do {                                                          \
        if (w < 14) asm volatile("s_waitcnt vmcnt(3)\n\ts_barrier" ::: "memory"); \
        else        asm volatile("s_waitcnt vmcnt(2)\n\ts_barrier" ::: "memory"); \
    } while (0)
#define WAITV0_BAR() asm volatile("s_waitcnt vmcnt(0)\n\ts_barrier" ::: "memory")
#define LGKM0_BAR()  asm volatile("s_waitcnt lgkmcnt(0)\n\ts_barrier" ::: "memory")
#define LGKM0()      asm volatile("s_waitcnt lgkmcnt(0)" ::: "memory")

__global__ __launch_bounds__(1024, 4)
void corr_mfma_kernel(const float* __restrict__ in1,
                      const float* __restrict__ in2,
                      float* __restrict__ out) {
    extern __shared__ __align__(16) char ldsbase[];
    float* S2 = (float*)ldsbase;               // [2][8ch][24r][40j] f32
    short* F  = (short*)(ldsbase + FOFFB);     // [4kb][960 rj][8e] bf16
    float* S1 = (float*)(ldsbase + S1OFFB);    // [2][8ch][16r][32px] f32
    float* EP = (float*)ldsbase;               // epilogue alias

    const int tid  = threadIdx.x;
    const int lane = tid & 63;
    const int w    = tid >> 6;                 // wave 0..15 = output row

    const int lin = blockIdx.x;                // 256 blocks, 1/CU
    const int b   = lin & 7;                   // batch == XCD
    const int idx = lin >> 3;                  // 0..31
    const int x0  = (idx & 3) * TW;
    const int y0  = (idx >> 2) * TY;

    const int i_px = lane & 15;
    const int kb   = lane >> 4;

    // ---- in2 DMA: 30 instr/step; waves 0-13: 2, 14-15: 1 ----
    const float* dsrc[2];
    int ddst[2];
    #pragma unroll
    for (int t = 0; t < 2; ++t) {
        if (t == 1 && w >= 14) { dsrc[t] = in2; ddst[t] = 0; continue; }
        const int q   = (w < 14) ? (w * 2 + t) : (28 + (w - 14));   // 0..29
        const int g   = q * 64 + lane;         // 0..1919
        const int ch  = g / 240;               // channel within 8-ch step
        const int rem = g % 240;
        const int r   = rem / 10;              // staged row 0..23
        const int jg  = rem % 10;              // 4-col granule
        int gy = y0 - 4 + r;
        int gx = x0 - 4 + jg * 4;
        gy = gy < 0 ? 0 : (gy > H_ - 1 ? H_ - 1 : gy);
        gx = gx < 0 ? 0 : (gx > W_ - 4 ? W_ - 4 : gx);   // pad=4 == granule
        dsrc[t] = in2 + ((long)(b * C_) + ch) * CS + gy * W_ + gx;
        ddst[t] = q * 1024;
    }
    // ---- in1 DMA: 16 instr/step, exactly 1/wave ----
    const float* d1src;
    int d1dst;
    {
        const int g   = w * 64 + lane;         // 0..1023
        const int ch  = g >> 7;                // 0..7
        const int rem = g & 127;
        const int r   = rem >> 3;              // 0..15
        const int xg  = rem & 7;               // 4-px granule
        d1src = in1 + ((long)(b * C_) + ch) * CS + (y0 + r) * W_ + x0 + xg * 4;
        d1dst = w * 1024;
    }

    // ---- convert descriptor (in2): 960 items/step, tid<960 ----
    const bool cact = (tid < 960);
    const int  crr  = tid / 40, cjj = tid % 40;
    const bool cval = cact && ((unsigned)(y0 - 4 + crr) < (unsigned)H_) &&
                              ((unsigned)(x0 - 4 + cjj) < (unsigned)W_);

    v4f acc0[2][ND];
    v4f acc1[2][5];
    #pragma unroll
    for (int t = 0; t < 2; ++t) {
        #pragma unroll
        for (int d = 0; d < ND; ++d) acc0[t][d] = (v4f)0.0f;
        #pragma unroll
        for (int p = 0; p < 5; ++p)  acc1[t][p] = (v4f)0.0f;
    }
    v8s afA[2], afB[2];                        // ONLY register pipeline state

#define ISSUE_G(s_) do {                                                      \
        const long so = (long)(s_) * 8 * CS;                                  \
        char* db2 = (char*)S2 + ((s_) & 1) * 30720;                           \
        dma16(dsrc[0] + so, db2 + ddst[0]);                                   \
        if (w < 14) dma16(dsrc[1] + so, db2 + ddst[1]);                       \
        dma16(d1src + so, (char*)ldsbase + S1OFFB + ((s_) & 1) * 16384 + d1dst); \
        FENCE();                                                              \
    } while (0)

#define CONVERT(s_) do {                                                      \
        if (cact) {                                                           \
            const float* sh = S2 + ((s_) & 1) * SB2F;                         \
            v8s pk;                                                           \
            _Pragma("unroll")                                                 \
            for (int e = 0; e < 8; ++e)                                       \
                pk[e] = (short)f2bf(sh[e * 960 + tid]);                       \
            if (!cval) pk = (v8s)0;                                           \
            *(v8s*)&F[(((s_) & 3) * 960 + tid) * 8] = pk;                     \
        }                                                                     \
    } while (0)

    // lane builds its A-frag from its own kb's slab (slab sl_, chunk sl_>>2)
#define ABUILD(sl_, AF_) do {                                                 \
        if (kb == ((sl_) & 3)) {                                              \
            const float* sl = S1 + ((sl_) & 1) * 4096;                        \
            _Pragma("unroll")                                                 \
            for (int t = 0; t < 2; ++t)                                       \
                _Pragma("unroll")                                             \
                for (int e = 0; e < 8; ++e)                                   \
                    AF_[t][e] = (short)f2bf(sl[e * 512 + w * 32 + t * 16 + i_px]); \
        }                                                                     \
    } while (0)

#define MFMA_C(AF_) do {                                                      \
        _Pragma("unroll")                                                     \
        for (int t = 0; t < 2; ++t) {                                         \
            _Pragma("unroll")                                                 \
            for (int dy = 0; dy < ND; ++dy) {                                 \
                const int rj = (w + dy) * 40 + t * 16 + i_px;                 \
                const v8s f = *(const v8s*)&F[(kb * 960 + rj) * 8];           \
                acc0[t][dy] = __builtin_amdgcn_mfma_f32_16x16x32_bf16(        \
                    AF_[t], f, acc0[t][dy], 0, 0, 0);                         \
            }                                                                 \
            const int hi = i_px >> 3, j1 = t * 16 + 16 + (i_px & 7);          \
            _Pragma("unroll")                                                 \
            for (int P = 0; P < 5; ++P) {                                     \
                int r = w + 2 * P + hi;                                       \
                if (r > 23) r = 23;        /* garbage lanes, never read */    \
                const v8s f = *(const v8s*)&F[(kb * 960 + r * 40 + j1) * 8];  \
                acc1[t][P] = __builtin_amdgcn_mfma_f32_16x16x32_bf16(         \
                    AF_[t], f, acc1[t][P], 0, 0, 0);                          \
            }                                                                 \
        }                                                                     \
    } while (0)

#define RA(s_, DOM_, AF_) do {                                                \
        if ((s_) + 2 <= 31) ISSUE_G((s_) + 2);                                \
        if (DOM_) MFMA_C(AF_);                                                \
        if ((s_) + 2 <= 31)      { WAITK_BAR(); }                             \
        else if ((s_) == 30)     { WAITV0_BAR(); }                            \
    } while (0)

#define RB(s_, AF_) do {                                                      \
        if ((s_) < 31) {                                                      \
            CONVERT((s_) + 1);                                                \
            ABUILD((s_) + 1, AF_);                                            \
            LGKM0_BAR();                                                      \
        }                                                                     \
    } while (0)

#define CHUNK(c_, AFc_, AFn_) do {                                            \
        RA(4*(c_)+0, false, AFc_); RB(4*(c_)+0, AFc_);                        \
        RA(4*(c_)+1, false, AFc_); RB(4*(c_)+1, AFc_);                        \
        RA(4*(c_)+2, false, AFc_); RB(4*(c_)+2, AFc_);                        \
        RA(4*(c_)+3, true,  AFc_); RB(4*(c_)+3, AFn_);                        \
    } while (0)

    // ---- prologue: G(0), G(1); convert(0) + chunk0/kb0 A-frag ----
    ISSUE_G(0);
    ISSUE_G(1);
    WAITK_BAR();
    CONVERT(0);
    ABUILD(0, afA);
    LGKM0_BAR();

    // ---- 8 chunks = 32 steps ----
    CHUNK(0, afA, afB);
    CHUNK(1, afB, afA);
    CHUNK(2, afA, afB);
    CHUNK(3, afB, afA);
    CHUNK(4, afA, afB);
    CHUNK(5, afB, afA);
    CHUNK(6, afA, afB);
    CHUNK(7, afB, afA);

    // ---- epilogue: 1 row x 2 n-tiles per wave, wave-private EP ----
    float* epw = EP + w * 384;
    const int g4 = lane >> 4;
    #pragma unroll
    for (int t = 0; t < 2; ++t) {
        #pragma unroll
        for (int dy = 0; dy < ND; ++dy) {
            #pragma unroll
            for (int q = 0; q < 4; ++q)
                epw[(g4 * 4 + q) * 24 + i_px] = acc0[t][dy][q];
            if ((i_px >> 3) == (dy & 1)) {
                #pragma unroll
                for (int q = 0; q < 4; ++q)
                    epw[(g4 * 4 + q) * 24 + 16 + (i_px & 7)] = acc1[t][dy >> 1][q];
            }
            LGKM0();
            #pragma unroll
            for (int rep = 0; rep < 3; ++rep) {
                const int dx = g4 + rep * 4;
                if (dx < 9) {
                    const float v = epw[i_px * 24 + i_px + dx] * (1.0f / 256.0f);
                    out[((long)b * 81 + dy * 9 + dx) * CS + (y0 + w) * W_ + x0 + t * 16 + i_px] = v;
                }
            }
            LGKM0();
        }
    }
#undef ISSUE_G
#undef CONVERT
#undef ABUILD
#undef MFMA_C
#undef RA
#undef RB
#undef CHUNK
}

extern "C" void kernel_launch(void* const* d_in, const int* in_sizes, int n_in,
                              void* d_out, int out_size, void* d_ws, size_t ws_size,
                              hipStream_t stream) {
    const float* in1 = (const float*)d_in[0];
    const float* in2 = (const float*)d_in[1];
    float* outp      = (float*)d_out;
    (void)hipFuncSetAttribute((const void*)corr_mfma_kernel,
                              hipFuncAttributeMaxDynamicSharedMemorySize,
                              LDS_TOTAL);
    corr_mfma_kernel<<<256, 1024, LDS_TOTAL, stream>>>(in1, in2, outp);
}

// Round 14
// 88.951 us; speedup vs baseline: 2.9028x; 2.5183x over previous
//
#include <hip/hip_runtime.h>

// Correlation layer: in1,in2 [8,256,128,128] f32 -> out [8,81,128,128] f32
// out[b, dy*9+dx, y, x] = mean_c in1[b,c,y,x] * in2pad[b,c,y+dy,x+dx], pad=4
//
// v14 = v11 geometry (tile 16x16, 472 MB requests) at 16 waves/1024 thr:
// 1 ROW PER WAVE -> acc = 14 v4f = 56 regs, fits the 128-reg budget that
// 4 waves/SIMD implies (v12/v13's spill cause). Zero reg pipeline state:
// both inputs via global_load_lds (S2 16-ch dbuf halves; S1 in1 dbuf; F bf16
// single 32-ch chunk; FA in1 frags). Two-rendezvous schedule, keep vmcnt(4)/(3).

#define B_   8
#define C_   256
#define H_   128
#define W_   128
#define ND   9
#define TY   16
#define TW   16
#define CS   (H_ * W_)
#define NST  16                  // 16-ch steps per tile
#define SB2  9216                // floats per S2 half (16*24*24)
#define S1OFF 73728
#define FOFF  106496
#define FAOFF 143360
#define LDS_TOTAL 159744

typedef short v8s __attribute__((ext_vector_type(8)));
typedef float v4f __attribute__((ext_vector_type(4)));

__device__ __forceinline__ unsigned short f2bf(float f) {
    union { float f; unsigned u; } v; v.f = f;
    return (unsigned short)((v.u + 0x7FFFu + ((v.u >> 16) & 1u)) >> 16);
}

__device__ __forceinline__ void dma16(const float* g, void* lds) {
    __builtin_amdgcn_global_load_lds(
        (const __attribute__((address_space(1))) void*)g,
        (__attribute__((address_space(3))) void*)lds, 16, 0, 0);
}

#define FENCE()     asm volatile("" ::: "memory")
// retire G(s+1), keep G(s+2): per-wave ops/G = 4 (w<4: 3 in2 + 1 in1) else 3
#define WAITK_BAR() do {                                                          \
        if (w < 4) asm volatile("s_waitcnt vmcnt(4)\n\ts_barrier" ::: "memory");  \
        else       asm volatile("s_waitcnt vmcnt(3)\n\ts_barrier" ::: "memory");  \
    } while (0)
#define WAITV0_BAR() asm volatile("s_waitcnt vmcnt(0)\n\ts_barrier" ::: "memory")
#define LGKM0_BAR()  asm volatile("s_waitcnt lgkmcnt(0)\n\ts_barrier" ::: "memory")
#define LGKM0()      asm volatile("s_waitcnt lgkmcnt(0)" ::: "memory")

__global__ __launch_bounds__(1024, 4)
void corr_mfma_kernel(const float* __restrict__ in1,
                      const float* __restrict__ in2,
                      float* __restrict__ out) {
    extern __shared__ __align__(16) char ldsbase[];
    float* S2 = (float*)ldsbase;               // [2][16ch][24r][24j] f32
    float* S1 = (float*)(ldsbase + S1OFF);     // [2][16ch][16r][16x] f32
    short* F  = (short*)(ldsbase + FOFF);      // [4kb][576 rj][8e] bf16 (1 chunk)
    short* FA = (short*)(ldsbase + FAOFF);     // [16r][16px][32ch] bf16
    float* EP = (float*)ldsbase;               // epilogue alias (S2 free then)

    const int tid  = threadIdx.x;
    const int lane = tid & 63;
    const int w    = tid >> 6;                 // wave 0..15 = output row

    const int lin = blockIdx.x;                // 512 blocks
    const int b   = lin & 7;                   // batch == XCD
    const int idx = lin >> 3;                  // 0..63
    const int x0  = (idx & 7) * TW;
    const int y0  = (idx >> 3) * TY;

    const int i_px = lane & 15;
    const int kb   = lane >> 4;

    // ---- in2 DMA: 36 granule-instr; waves 0-3: 3, waves 4-15: 2 ----
    const float* dsrc[3];
    int ddst[3];
    #pragma unroll
    for (int t = 0; t < 3; ++t) {
        if (w >= 4 && t >= 2) { dsrc[t] = in2; ddst[t] = 0; continue; }
        const int q   = (w < 4) ? (w * 3 + t) : (12 + (w - 4) * 2 + t);  // 0..35
        const int g   = q * 64 + lane;         // 0..2303
        const int ccl = g / 144;               // channel within 16-ch step
        const int rem = g % 144;
        const int r   = rem / 6;               // staged row 0..23
        const int jg  = rem % 6;               // 4-col granule
        int gy = y0 - 4 + r;
        int gx = x0 - 4 + jg * 4;
        gy = gy < 0 ? 0 : (gy > H_ - 1 ? H_ - 1 : gy);
        gx = gx < 0 ? 0 : (gx > W_ - 4 ? W_ - 4 : gx);   // pad=4 == granule
        dsrc[t] = in2 + ((long)(b * C_) + ccl) * CS + gy * W_ + gx;
        ddst[t] = q * 1024;
    }
    // ---- in1 DMA: 16 granule-instr, exactly 1/wave ----
    const float* d1src;
    int d1dst;
    {
        const int g   = w * 64 + lane;         // 0..1023
        const int ch  = g >> 6;                // 0..15
        const int rem = g & 63;
        const int r   = rem >> 2;
        const int xg  = rem & 3;
        d1src = in1 + ((long)(b * C_) + ch) * CS + (y0 + r) * W_ + x0 + xg * 4;
        d1dst = w * 1024;
    }

    // ---- convert descriptors: in2 1152 items/step (it0 all, it1 tid<128) ----
    int rem_i[2], kbl_i[2];
    bool cval[2];
    #pragma unroll
    for (int it = 0; it < 2; ++it) {
        const int s2 = tid + it * 1024;        // 0..1151 (it1 only tid<128)
        kbl_i[it] = s2 / 576;
        rem_i[it] = s2 % 576;                  // r*24+j
        const int r = rem_i[it] / 24, j = rem_i[it] % 24;
        cval[it] = ((unsigned)(y0 - 4 + r) < (unsigned)H_) &&
                   ((unsigned)(x0 - 4 + j) < (unsigned)W_);
    }
    const int r1  = (tid >> 5) & 15;           // in1: 512 items, tid<512
    const int px1 = (tid >> 1) & 15;
    const int kb1 = tid & 1;

    v4f acc0[ND];
    v4f acc1[5];
    #pragma unroll
    for (int d = 0; d < ND; ++d) acc0[d] = (v4f)0.0f;
    #pragma unroll
    for (int p = 0; p < 5; ++p)  acc1[p] = (v4f)0.0f;

#define ISSUE_G(s_) do {                                                      \
        const long so = (long)(s_) * 16 * CS;                                 \
        char* sb2 = (char*)S2 + ((s_) & 1) * 36864;                           \
        _Pragma("unroll")                                                     \
        for (int t = 0; t < 3; ++t)                                           \
            if (w < 4 || t < 2) dma16(dsrc[t] + so, sb2 + ddst[t]);           \
        dma16(d1src + so, (char*)ldsbase + S1OFF + ((s_) & 1) * 16384 + d1dst); \
        FENCE();                                                              \
    } while (0)

#define CONVERT(s_) do {                                                      \
        const float* sb2 = S2 + ((s_) & 1) * SB2;                             \
        _Pragma("unroll")                                                     \
        for (int it = 0; it < 2; ++it) {                                      \
            if (it < 1 || tid < 128) {                                        \
                v8s pk;                                                       \
                _Pragma("unroll")                                             \
                for (int e = 0; e < 8; ++e)                                   \
                    pk[e] = (short)f2bf(sb2[kbl_i[it] * 4608 + rem_i[it] + e * 576]); \
                if (!cval[it]) pk = (v8s)0;                                   \
                const int kb32 = ((s_) & 1) * 2 + kbl_i[it];                  \
                *(v8s*)&F[kb32 * 4608 + (rem_i[it] << 3)] = pk;               \
            }                                                                 \
        }                                                                     \
        if (tid < 512) {                                                      \
            const float* sb1 = S1 + ((s_) & 1) * 4096;                        \
            v8s pa;                                                           \
            _Pragma("unroll")                                                 \
            for (int e = 0; e < 8; ++e)                                       \
                pa[e] = (short)f2bf(sb1[(kb1 * 8 + e) * 256 + r1 * 16 + px1]); \
            *(v8s*)&FA[r1 * 512 + px1 * 32 + ((s_) & 1) * 16 + kb1 * 8] = pa; \
        }                                                                     \
    } while (0)

    // ---- prologue ----
    ISSUE_G(0);
    ISSUE_G(1);
    WAITK_BAR();                   // all waves' step-0 DMA landed; G(1) in flight
    CONVERT(0);
    LGKM0_BAR();

    // ---- main: 16 steps ----
    #pragma unroll
    for (int s = 0; s < NST; ++s) {
        // region A: issue step s+2; MFMA chunk s>>1 on odd steps
        if (s + 2 < NST) ISSUE_G(s + 2);

        if (s & 1) {
            const v8s af = *(const v8s*)&FA[w * 512 + i_px * 32 + kb * 8];
            #pragma unroll
            for (int dy = 0; dy < ND; ++dy) {
                const int rj = (w + dy) * 24 + i_px;
                const v8s f = *(const v8s*)&F[kb * 4608 + (rj << 3)];
                acc0[dy] = __builtin_amdgcn_mfma_f32_16x16x32_bf16(
                    af, f, acc0[dy], 0, 0, 0);
            }
            const int hi = i_px >> 3, j1 = 16 + (i_px & 7);
            #pragma unroll
            for (int P = 0; P < 5; ++P) {
                int r = w + 2 * P + hi;
                if (r > 23) r = 23;            // (w15,P4,hi1) garbage, unused
                const int rj = r * 24 + j1;
                const v8s f = *(const v8s*)&F[kb * 4608 + (rj << 3)];
                acc1[P] = __builtin_amdgcn_mfma_f32_16x16x32_bf16(
                    af, f, acc1[P], 0, 0, 0);
            }
        }

        // rendezvous: retire G(s+1), keep G(s+2) in flight
        if (s + 2 < NST)       { WAITK_BAR(); }
        else if (s == NST - 2) { WAITV0_BAR(); }

        // region B: convert step s+1
        if (s < NST - 1) {
            CONVERT(s + 1);
            LGKM0_BAR();
        }
    }

    // ---- epilogue: 1 row/wave, wave-private EP scratch (aliases S2) ----
    float* epw = EP + w * 384;
    const int g4 = lane >> 4;
    #pragma unroll
    for (int dy = 0; dy < ND; ++dy) {
        #pragma unroll
        for (int q = 0; q < 4; ++q)
            epw[(g4 * 4 + q) * 24 + i_px] = acc0[dy][q];
        if ((i_px >> 3) == (dy & 1)) {
            #pragma unroll
            for (int q = 0; q < 4; ++q)
                epw[(g4 * 4 + q) * 24 + 16 + (i_px & 7)] = acc1[dy >> 1][q];
        }
        LGKM0();
        #pragma unroll
        for (int rep = 0; rep < 3; ++rep) {
            const int dx = g4 + rep * 4;
            if (dx < 9) {
                const float v = epw[i_px * 24 + i_px + dx] * (1.0f / 256.0f);
                out[((long)b * 81 + dy * 9 + dx) * CS + (y0 + w) * W_ + x0 + i_px] = v;
            }
        }
        LGKM0();
    }
}

extern "C" void kernel_launch(void* const* d_in, const int* in_sizes, int n_in,
                              void* d_out, int out_size, void* d_ws, size_t ws_size,
                              hipStream_t stream) {
    const float* in1 = (const float*)d_in[0];
    const float* in2 = (const float*)d_in[1];
    float* outp      = (float*)d_out;
    (void)hipFuncSetAttribute((const void*)corr_mfma_kernel,
                              hipFuncAttributeMaxDynamicSharedMemorySize,
                              LDS_TOTAL);
    corr_mfma_kernel<<<512, 1024, LDS_TOTAL, stream>>>(in1, in2, outp);
}

// Round 15
// 84.791 us; speedup vs baseline: 3.0452x; 1.0491x over previous
//
#include <hip/hip_runtime.h>

// Correlation layer: in1,in2 [8,256,128,128] f32 -> out [8,81,128,128] f32
// out[b, dy*9+dx, y, x] = mean_c in1[b,c,y,x] * in2pad[b,c,y+dy,x+dx], pad=4
//
// v15 = v14 with DEPTH-2 DMA prefetch (queue never drains at the rendezvous):
// 8-ch steps, 3-slot S2/S1 rings, issue G(s+3) at step s, retire G(s+1) with
// TWO groups kept in flight. F = one 32-ch chunk (kb group s%4; MFMA at
// s%4==3). Tile 16x16, 16 waves, 1 row/wave (acc 56 regs fits 128 budget),
// zero register pipeline state (both inputs via global_load_lds).

#define B_   8
#define C_   256
#define H_   128
#define W_   128
#define ND   9
#define TY   16
#define TW   16
#define CS   (H_ * W_)
#define NST  32                  // 8-ch steps per tile
#define S2SLOT 18432             // bytes per S2 slot (8ch*24*24*4)
#define S1SLOT 8192              // bytes per S1 slot (8ch*16*16*4)
#define S1OFF  55296             // 3*S2SLOT
#define FOFF   79872             // +3*S1SLOT
#define FAOFF  116736            // +36864 (F)
#define LDS_TOTAL 133120         // +16384 (FA)

typedef short v8s __attribute__((ext_vector_type(8)));
typedef float v4f __attribute__((ext_vector_type(4)));

__device__ __forceinline__ unsigned short f2bf(float f) {
    union { float f; unsigned u; } v; v.f = f;
    return (unsigned short)((v.u + 0x7FFFu + ((v.u >> 16) & 1u)) >> 16);
}

__device__ __forceinline__ void dma16(const float* g, void* lds) {
    __builtin_amdgcn_global_load_lds(
        (const __attribute__((address_space(1))) void*)g,
        (__attribute__((address_space(3))) void*)lds, 16, 0, 0);
}

#define FENCE()     asm volatile("" ::: "memory")
// per-wave ops/group: w0-1: 2, w2-7: 1, w8-15: 2
// steady: retire G(s+1), keep G(s+2)+G(s+3) = 2 groups
#define WAITK2_BAR() do {                                                         \
        if (w >= 2 && w < 8) asm volatile("s_waitcnt vmcnt(2)\n\ts_barrier" ::: "memory"); \
        else                 asm volatile("s_waitcnt vmcnt(4)\n\ts_barrier" ::: "memory"); \
    } while (0)
// tail (s==29): keep G(31) only = 1 group
#define WAITK1_BAR() do {                                                         \
        if (w >= 2 && w < 8) asm volatile("s_waitcnt vmcnt(1)\n\ts_barrier" ::: "memory"); \
        else                 asm volatile("s_waitcnt vmcnt(2)\n\ts_barrier" ::: "memory"); \
    } while (0)
#define WAITV0_BAR() asm volatile("s_waitcnt vmcnt(0)\n\ts_barrier" ::: "memory")
#define LGKM0_BAR()  asm volatile("s_waitcnt lgkmcnt(0)\n\ts_barrier" ::: "memory")
#define LGKM0()      asm volatile("s_waitcnt lgkmcnt(0)" ::: "memory")

__global__ __launch_bounds__(1024, 4)
void corr_mfma_kernel(const float* __restrict__ in1,
                      const float* __restrict__ in2,
                      float* __restrict__ out) {
    extern __shared__ __align__(16) char ldsbase[];
    float* S2 = (float*)ldsbase;               // [3][8ch][24r][24j] f32
    float* S1 = (float*)(ldsbase + S1OFF);     // [3][8ch][16r][16x] f32
    short* F  = (short*)(ldsbase + FOFF);      // [4kb][576 rj][8e] bf16
    short* FA = (short*)(ldsbase + FAOFF);     // [16r][16px][32ch] bf16
    float* EP = (float*)ldsbase;               // epilogue alias (S2 dead then)

    const int tid  = threadIdx.x;
    const int lane = tid & 63;
    const int w    = tid >> 6;                 // wave 0..15 = output row

    const int lin = blockIdx.x;                // 512 blocks
    const int b   = lin & 7;                   // batch == XCD
    const int idx = lin >> 3;                  // 0..63
    const int x0  = (idx & 7) * TW;
    const int y0  = (idx >> 3) * TY;

    const int i_px = lane & 15;
    const int kb   = lane >> 4;

    // ---- in2 DMA: 18 instr/step; w0-1: 2, w2-15: 1 ----
    const float* dsrc[2];
    int ddst[2];
    #pragma unroll
    for (int t = 0; t < 2; ++t) {
        if (t == 1 && w >= 2) { dsrc[t] = in2; ddst[t] = 0; continue; }
        const int q   = (w < 2) ? (w * 2 + t) : (4 + (w - 2));   // 0..17
        const int g   = q * 64 + lane;         // 0..1151
        const int ch  = g / 144;               // channel within 8-ch step
        const int rem = g % 144;
        const int r   = rem / 6;               // staged row 0..23
        const int jg  = rem % 6;               // 4-col granule
        int gy = y0 - 4 + r;
        int gx = x0 - 4 + jg * 4;
        gy = gy < 0 ? 0 : (gy > H_ - 1 ? H_ - 1 : gy);
        gx = gx < 0 ? 0 : (gx > W_ - 4 ? W_ - 4 : gx);   // pad=4 == granule
        dsrc[t] = in2 + ((long)(b * C_) + ch) * CS + gy * W_ + gx;
        ddst[t] = q * 1024;
    }
    // ---- in1 DMA: 8 instr/step, waves 8-15 one each ----
    const float* d1src = in2;  // dummy for idle waves
    int d1dst = 0;
    if (w >= 8) {
        const int q   = w - 8;                 // 0..7
        const int g   = q * 64 + lane;         // 0..511
        const int ch  = g >> 6;                // 0..7
        const int rem = g & 63;
        const int r   = rem >> 2;
        const int xg  = rem & 3;
        d1src = in1 + ((long)(b * C_) + ch) * CS + (y0 + r) * W_ + x0 + xg * 4;
        d1dst = q * 1024;
    }

    // ---- convert descriptors ----
    // in2: 576 items/step (tid<576): item packs 8ch at one rj
    const bool c2act = (tid < 576);
    const int  crr   = tid / 24, cjj = tid % 24;
    const bool c2val = c2act && ((unsigned)(y0 - 4 + crr) < (unsigned)H_) &&
                                ((unsigned)(x0 - 4 + cjj) < (unsigned)W_);
    // in1: 256 items/step (tid<256): item packs 8ch at one (r,px)
    const bool c1act = (tid < 256);

    v4f acc0[ND];
    v4f acc1[5];
    #pragma unroll
    for (int d = 0; d < ND; ++d) acc0[d] = (v4f)0.0f;
    #pragma unroll
    for (int p = 0; p < 5; ++p)  acc1[p] = (v4f)0.0f;

#define ISSUE_G(s_) do {                                                      \
        const long so = (long)(s_) * 8 * CS;                                  \
        char* sb2 = (char*)S2 + ((s_) % 3) * S2SLOT;                          \
        dma16(dsrc[0] + so, sb2 + ddst[0]);                                   \
        if (w < 2) dma16(dsrc[1] + so, sb2 + ddst[1]);                        \
        if (w >= 8)                                                           \
            dma16(d1src + so, (char*)ldsbase + S1OFF + ((s_) % 3) * S1SLOT + d1dst); \
        FENCE();                                                              \
    } while (0)

#define CONVERT(s_) do {                                                      \
        if (c2act) {                                                          \
            const float* sh = S2 + ((s_) % 3) * 4608;                         \
            v8s pk;                                                           \
            _Pragma("unroll")                                                 \
            for (int e = 0; e < 8; ++e)                                       \
                pk[e] = (short)f2bf(sh[e * 576 + tid]);                       \
            if (!c2val) pk = (v8s)0;                                          \
            *(v8s*)&F[(((s_) & 3) * 576 + tid) * 8] = pk;                     \
        }                                                                     \
        if (c1act) {                                                          \
            const float* sa = S1 + ((s_) % 3) * 2048;                         \
            v8s pa;                                                           \
            _Pragma("unroll")                                                 \
            for (int e = 0; e < 8; ++e)                                       \
                pa[e] = (short)f2bf(sa[e * 256 + tid]);                       \
            *(v8s*)&FA[tid * 32 + ((s_) & 3) * 8] = pa;                       \
        }                                                                     \
    } while (0)

    // ---- prologue: fill the 3-deep pipe ----
    ISSUE_G(0);
    ISSUE_G(1);
    ISSUE_G(2);
    WAITK2_BAR();                  // retire G(0); G(1),G(2) in flight
    CONVERT(0);
    LGKM0_BAR();

    // ---- main: 32 steps ----
    #pragma unroll
    for (int s = 0; s < NST; ++s) {
        // region A: issue step s+3; MFMA chunk s>>2 on s%4==3
        if (s + 3 < NST) ISSUE_G(s + 3);

        if ((s & 3) == 3) {
            const v8s af = *(const v8s*)&FA[w * 512 + i_px * 32 + kb * 8];
            #pragma unroll
            for (int dy = 0; dy < ND; ++dy) {
                const int rj = (w + dy) * 24 + i_px;
                const v8s f = *(const v8s*)&F[kb * 4608 + (rj << 3)];
                acc0[dy] = __builtin_amdgcn_mfma_f32_16x16x32_bf16(
                    af, f, acc0[dy], 0, 0, 0);
            }
            const int hi = i_px >> 3, j1 = 16 + (i_px & 7);
            #pragma unroll
            for (int P = 0; P < 5; ++P) {
                int r = w + 2 * P + hi;
                if (r > 23) r = 23;            // (w15,P4,hi1) garbage, unused
                const int rj = r * 24 + j1;
                const v8s f = *(const v8s*)&F[kb * 4608 + (rj << 3)];
                acc1[P] = __builtin_amdgcn_mfma_f32_16x16x32_bf16(
                    af, f, acc1[P], 0, 0, 0);
            }
        }

        // rendezvous: retire G(s+1)
        if (s + 3 < NST)       { WAITK2_BAR(); }   // keep 2 groups
        else if (s == NST - 3) { WAITK1_BAR(); }   // keep G(31)
        else if (s == NST - 2) { WAITV0_BAR(); }

        // region B: convert step s+1
        if (s < NST - 1) {
            CONVERT(s + 1);
            LGKM0_BAR();
        }
    }

    // ---- epilogue: 1 row/wave, wave-private EP scratch (aliases S2) ----
    float* epw = EP + w * 384;
    const int g4 = lane >> 4;
    #pragma unroll
    for (int dy = 0; dy < ND; ++dy) {
        #pragma unroll
        for (int q = 0; q < 4; ++q)
            epw[(g4 * 4 + q) * 24 + i_px] = acc0[dy][q];
        if ((i_px >> 3) == (dy & 1)) {
            #pragma unroll
            for (int q = 0; q < 4; ++q)
                epw[(g4 * 4 + q) * 24 + 16 + (i_px & 7)] = acc1[dy >> 1][q];
        }
        LGKM0();
        #pragma unroll
        for (int rep = 0; rep < 3; ++rep) {
            const int dx = g4 + rep * 4;
            if (dx < 9) {
                const float v = epw[i_px * 24 + i_px + dx] * (1.0f / 256.0f);
                out[((long)b * 81 + dy * 9 + dx) * CS + (y0 + w) * W_ + x0 + i_px] = v;
            }
        }
        LGKM0();
    }
#undef ISSUE_G
#undef CONVERT
}

extern "C" void kernel_launch(void* const* d_in, const int* in_sizes, int n_in,
                              void* d_out, int out_size, void* d_ws, size_t ws_size,
                              hipStream_t stream) {
    const float* in1 = (const float*)d_in[0];
    const float* in2 = (const float*)d_in[1];
    float* outp      = (float*)d_out;
    (void)hipFuncSetAttribute((const void*)corr_mfma_kernel,
                              hipFuncAttributeMaxDynamicSharedMemorySize,
                              LDS_TOTAL);
    corr_mfma_kernel<<<512, 1024, LDS_TOTAL, stream>>>(in1, in2, outp);
}

// Round 16
// 83.226 us; speedup vs baseline: 3.1025x; 1.0188x over previous
//
#include <hip/hip_runtime.h>

// Correlation layer: in1,in2 [8,256,128,128] f32 -> out [8,81,128,128] f32
// out[b, dy*9+dx, y, x] = mean_c in1[b,c,y,x] * in2pad[b,c,y+dy,x+dx], pad=4
//
// v16 = v15 with fused single-barrier steps (64 -> 41 barriers/tile):
// per step: [RA: issue G(s+4); MFMA if s%4==3 (+lgkm0+bar only there)]
//           [RB: convert(s+1)] [END: s_waitcnt vmcnt(keep2) lgkmcnt(0); bar].
// 4-slot S2/S1 rings (issue leads read by 4), depth-2 in flight maintained.
// Tile 16x16, 16 waves, 1 row/wave (acc 56 regs), zero reg pipeline state.

#define B_   8
#define C_   256
#define H_   128
#define W_   128
#define ND   9
#define TY   16
#define TW   16
#define CS   (H_ * W_)
#define NST  32                  // 8-ch steps per tile
#define S2SLOT 18432             // bytes per S2 slot (8ch*24*24*4)
#define S1SLOT 8192              // bytes per S1 slot (8ch*16*16*4)
#define S1OFF  73728             // 4*S2SLOT
#define FOFF   106496            // +4*S1SLOT
#define FAOFF  143360            // +36864 (F)
#define LDS_TOTAL 159744         // +16384 (FA)

typedef short v8s __attribute__((ext_vector_type(8)));
typedef float v4f __attribute__((ext_vector_type(4)));

__device__ __forceinline__ unsigned short f2bf(float f) {
    union { float f; unsigned u; } v; v.f = f;
    return (unsigned short)((v.u + 0x7FFFu + ((v.u >> 16) & 1u)) >> 16);
}

__device__ __forceinline__ void dma16(const float* g, void* lds) {
    __builtin_amdgcn_global_load_lds(
        (const __attribute__((address_space(1))) void*)g,
        (__attribute__((address_space(3))) void*)lds, 16, 0, 0);
}

#define FENCE()     asm volatile("" ::: "memory")
// fused end-of-step: retire G(s+2), keep 2 groups; lgkm drain; barrier
// per-wave ops/group: w0-1: 2, w2-7: 1, w8-15: 2
#define ENDK2_BAR() do {                                                          \
        if (w >= 2 && w < 8) asm volatile("s_waitcnt vmcnt(2) lgkmcnt(0)\n\ts_barrier" ::: "memory"); \
        else                 asm volatile("s_waitcnt vmcnt(4) lgkmcnt(0)\n\ts_barrier" ::: "memory"); \
    } while (0)
#define ENDK1_BAR() do {                                                          \
        if (w >= 2 && w < 8) asm volatile("s_waitcnt vmcnt(1) lgkmcnt(0)\n\ts_barrier" ::: "memory"); \
        else                 asm volatile("s_waitcnt vmcnt(2) lgkmcnt(0)\n\ts_barrier" ::: "memory"); \
    } while (0)
#define ENDK0_BAR()  asm volatile("s_waitcnt vmcnt(0) lgkmcnt(0)\n\ts_barrier" ::: "memory")
#define LG_BAR()     asm volatile("s_waitcnt lgkmcnt(0)\n\ts_barrier" ::: "memory")
#define LGKM0()      asm volatile("s_waitcnt lgkmcnt(0)" ::: "memory")

__global__ __launch_bounds__(1024, 4)
void corr_mfma_kernel(const float* __restrict__ in1,
                      const float* __restrict__ in2,
                      float* __restrict__ out) {
    extern __shared__ __align__(16) char ldsbase[];
    float* S2 = (float*)ldsbase;               // [4][8ch][24r][24j] f32
    float* S1 = (float*)(ldsbase + S1OFF);     // [4][8ch][16r][16x] f32
    short* F  = (short*)(ldsbase + FOFF);      // [4kb][576 rj][8e] bf16
    short* FA = (short*)(ldsbase + FAOFF);     // [16r][16px][32ch] bf16
    float* EP = (float*)ldsbase;               // epilogue alias (S2 dead then)

    const int tid  = threadIdx.x;
    const int lane = tid & 63;
    const int w    = tid >> 6;                 // wave 0..15 = output row

    const int lin = blockIdx.x;                // 512 blocks
    const int b   = lin & 7;                   // batch == XCD
    const int idx = lin >> 3;                  // 0..63
    const int x0  = (idx & 7) * TW;
    const int y0  = (idx >> 3) * TY;

    const int i_px = lane & 15;
    const int kb   = lane >> 4;

    // ---- in2 DMA: 18 instr/step; w0-1: 2, w2-15: 1 ----
    const float* dsrc[2];
    int ddst[2];
    #pragma unroll
    for (int t = 0; t < 2; ++t) {
        if (t == 1 && w >= 2) { dsrc[t] = in2; ddst[t] = 0; continue; }
        const int q   = (w < 2) ? (w * 2 + t) : (4 + (w - 2));   // 0..17
        const int g   = q * 64 + lane;         // 0..1151
        const int ch  = g / 144;               // channel within 8-ch step
        const int rem = g % 144;
        const int r   = rem / 6;               // staged row 0..23
        const int jg  = rem % 6;               // 4-col granule
        int gy = y0 - 4 + r;
        int gx = x0 - 4 + jg * 4;
        gy = gy < 0 ? 0 : (gy > H_ - 1 ? H_ - 1 : gy);
        gx = gx < 0 ? 0 : (gx > W_ - 4 ? W_ - 4 : gx);   // pad=4 == granule
        dsrc[t] = in2 + ((long)(b * C_) + ch) * CS + gy * W_ + gx;
        ddst[t] = q * 1024;
    }
    // ---- in1 DMA: 8 instr/step, waves 8-15 one each ----
    const float* d1src = in2;  // dummy for idle waves
    int d1dst = 0;
    if (w >= 8) {
        const int q   = w - 8;                 // 0..7
        const int g   = q * 64 + lane;         // 0..511
        const int ch  = g >> 6;                // 0..7
        const int rem = g & 63;
        const int r   = rem >> 2;
        const int xg  = rem & 3;
        d1src = in1 + ((long)(b * C_) + ch) * CS + (y0 + r) * W_ + x0 + xg * 4;
        d1dst = q * 1024;
    }

    // ---- convert descriptors ----
    const bool c2act = (tid < 576);            // in2: 576 items/step (8ch each)
    const int  crr   = tid / 24, cjj = tid % 24;
    const bool c2val = c2act && ((unsigned)(y0 - 4 + crr) < (unsigned)H_) &&
                                ((unsigned)(x0 - 4 + cjj) < (unsigned)W_);
    const bool c1act = (tid < 256);            // in1: 256 items/step (8ch each)

    v4f acc0[ND];
    v4f acc1[5];
    #pragma unroll
    for (int d = 0; d < ND; ++d) acc0[d] = (v4f)0.0f;
    #pragma unroll
    for (int p = 0; p < 5; ++p)  acc1[p] = (v4f)0.0f;

#define ISSUE_G(s_) do {                                                      \
        const long so = (long)(s_) * 8 * CS;                                  \
        char* sb2 = (char*)S2 + ((s_) & 3) * S2SLOT;                          \
        dma16(dsrc[0] + so, sb2 + ddst[0]);                                   \
        if (w < 2) dma16(dsrc[1] + so, sb2 + ddst[1]);                        \
        if (w >= 8)                                                           \
            dma16(d1src + so, (char*)ldsbase + S1OFF + ((s_) & 3) * S1SLOT + d1dst); \
        FENCE();                                                              \
    } while (0)

#define CONVERT(s_) do {                                                      \
        if (c2act) {                                                          \
            const float* sh = S2 + ((s_) & 3) * 4608;                         \
            v8s pk;                                                           \
            _Pragma("unroll")                                                 \
            for (int e = 0; e < 8; ++e)                                       \
                pk[e] = (short)f2bf(sh[e * 576 + tid]);                       \
            if (!c2val) pk = (v8s)0;                                          \
            *(v8s*)&F[(((s_) & 3) * 576 + tid) * 8] = pk;                     \
        }                                                                     \
        if (c1act) {                                                          \
            const float* sa = S1 + ((s_) & 3) * 2048;                         \
            v8s pa;                                                           \
            _Pragma("unroll")                                                 \
            for (int e = 0; e < 8; ++e)                                       \
                pa[e] = (short)f2bf(sa[e * 256 + tid]);                       \
            *(v8s*)&FA[tid * 32 + ((s_) & 3) * 8] = pa;                       \
        }                                                                     \
    } while (0)

    // ---- prologue: fill 4-deep pipe; retire G(0),G(1); convert(0) ----
    ISSUE_G(0);
    ISSUE_G(1);
    ISSUE_G(2);
    ISSUE_G(3);
    ENDK2_BAR();                   // retire G(0),G(1); keep G(2),G(3)
    CONVERT(0);
    LG_BAR();                      // convert(0) writes visible; S2 slot 0 free

    // ---- main: 32 steps, ONE fused barrier per step (+1 on MFMA steps) ----
    #pragma unroll
    for (int s = 0; s < NST; ++s) {
        // RA: issue step s+4 (slot s&3, freed by convert(s) last step)
        if (s + 4 < NST) ISSUE_G(s + 4);

        // MFMA chunk s>>2 on s%4==3, then midbar (F/FA WAR vs convert(s+1))
        if ((s & 3) == 3) {
            const v8s af = *(const v8s*)&FA[w * 512 + i_px * 32 + kb * 8];
            #pragma unroll
            for (int dy = 0; dy < ND; ++dy) {
                const int rj = (w + dy) * 24 + i_px;
                const v8s f = *(const v8s*)&F[kb * 4608 + (rj << 3)];
                acc0[dy] = __builtin_amdgcn_mfma_f32_16x16x32_bf16(
                    af, f, acc0[dy], 0, 0, 0);
            }
            const int hi = i_px >> 3, j1 = 16 + (i_px & 7);
            #pragma unroll
            for (int P = 0; P < 5; ++P) {
                int r = w + 2 * P + hi;
                if (r > 23) r = 23;            // (w15,P4,hi1) garbage, unused
                const int rj = r * 24 + j1;
                const v8s f = *(const v8s*)&F[kb * 4608 + (rj << 3)];
                acc1[P] = __builtin_amdgcn_mfma_f32_16x16x32_bf16(
                    af, f, acc1[P], 0, 0, 0);
            }
            if (s < NST - 1) LG_BAR();         // protect F/FA before next convert
        }

        // RB: convert step s+1
        if (s < NST - 1) CONVERT(s + 1);

        // END: fused retire + lgkm drain + barrier
        if (s + 4 < NST)       { ENDK2_BAR(); }   // retire G(s+2), keep 2 groups
        else if (s == NST - 4) { ENDK1_BAR(); }   // retire G(30), keep G(31)
        else if (s == NST - 3) { ENDK0_BAR(); }   // retire G(31)
        else if (s == NST - 2) { LG_BAR(); }      // convert(31) visible
        // s == NST-1: falls through to epilogue
    }

    // ---- epilogue: 1 row/wave, wave-private EP scratch (aliases S2) ----
    float* epw = EP + w * 384;
    const int g4 = lane >> 4;
    #pragma unroll
    for (int dy = 0; dy < ND; ++dy) {
        #pragma unroll
        for (int q = 0; q < 4; ++q)
            epw[(g4 * 4 + q) * 24 + i_px] = acc0[dy][q];
        if ((i_px >> 3) == (dy & 1)) {
            #pragma unroll
            for (int q = 0; q < 4; ++q)
                epw[(g4 * 4 + q) * 24 + 16 + (i_px & 7)] = acc1[dy >> 1][q];
        }
        LGKM0();
        #pragma unroll
        for (int rep = 0; rep < 3; ++rep) {
            const int dx = g4 + rep * 4;
            if (dx < 9) {
                const float v = epw[i_px * 24 + i_px + dx] * (1.0f / 256.0f);
                out[((long)b * 81 + dy * 9 + dx) * CS + (y0 + w) * W_ + x0 + i_px] = v;
            }
        }
        LGKM0();
    }
#undef ISSUE_G
#undef CONVERT
}

extern "C" void kernel_launch(void* const* d_in, const int* in_sizes, int n_in,
                              void* d_out, int out_size, void* d_ws, size_t ws_size,
                              hipStream_t stream) {
    const float* in1 = (const float*)d_in[0];
    const float* in2 = (const float*)d_in[1];
    float* outp      = (float*)d_out;
    (void)hipFuncSetAttribute((const void*)corr_mfma_kernel,
                              hipFuncAttributeMaxDynamicSharedMemorySize,
                              LDS_TOTAL);
    corr_mfma_kernel<<<512, 1024, LDS_TOTAL, stream>>>(in1, in2, outp);
}